// Round 3
// baseline (208.857 us; speedup 1.0000x reference)
//
#include <hip/hip_runtime.h>
#include <math.h>

// Group-limited MoE router, T=131072 tokens x E=256 experts.
// 8 lanes per token, one lane per expert-group (32 experts).
// Round 6: coalesced-load + wave-local LDS transpose. The old load pattern
// (lane reads 16B at stride 128B) touched 64 cachelines per instruction with
// 16B used each -> ~1 TB/s cold streaming. Now instruction j loads token j's
// full 1KB row lane-contiguously (64 lanes x 16B = 1KB, every line fully
// consumed by one instruction), then an XOR-swizzled LDS transpose hands each
// lane its private 32-expert slice. Compute phase identical to Round 5
// (byte-packed pix, DPP quad_perm, med3, per-round gating) -> bit-identical
// results.

#define SWZF(x, mask) __int_as_float(__builtin_amdgcn_ds_swizzle(__float_as_int(x), (((mask) << 10) | 0x1F)))
#define SWZI(x, mask) __builtin_amdgcn_ds_swizzle((x), (((mask) << 10) | 0x1F))
// DPP quad_perm codes: xor1 = [1,0,3,2] = 0xB1, xor2 = [2,3,0,1] = 0x4E,
// xor3 = [3,2,1,0] = 0x1B. Each token owns 8 aligned lanes -> quads never
// cross tokens, so quad_perm is safe for xor distances 1..3.
#define DPPF(x, ctrl) __int_as_float(__builtin_amdgcn_update_dpp(__float_as_int(x), __float_as_int(x), (ctrl), 0xF, 0xF, true))
#define DPPI(x, ctrl) __builtin_amdgcn_update_dpp((x), (x), (ctrl), 0xF, 0xF, true)
#define QP_X1 0xB1
#define QP_X2 0x4E
#define QP_X3 0x1B

__global__ __launch_bounds__(256) void router_topk_kernel(
    const float* __restrict__ logits,
    const float* __restrict__ bias,
    float* __restrict__ out_w,
    float* __restrict__ out_id,
    int T)
{
    const float NEGINF = -__builtin_inff();
    const int tid  = threadIdx.x;
    const int lane = tid & 63;
    const int wid  = tid >> 6;                  // wave id within block (0..3)
    const int s    = tid & 7;                   // expert-group owned by this lane
    const int tw   = (tid >> 3) & 7;            // token-in-wave (0..7)
    const int token = blockIdx.x * 32 + (tid >> 3);
    const int wtok0 = blockIdx.x * 32 + (wid << 3);

    // 4 waves x 512 float4 slots (8KB/wave) = 32KB
    __shared__ float4 xp[2048];
    float4* xw = xp + (wid << 9);               // this wave's private region

    // ---- coalesced load: instruction j covers token (wtok0+j)'s full 1KB row.
    // XOR-swizzled LDS slots: slot(j, chunk) = j*64 + (chunk ^ j); both the
    // b128 write (chunk = lane) and the later read are bank-balanced.
    {
        float4 g[8];
        #pragma unroll
        for (int j = 0; j < 8; ++j) {
            int r = wtok0 + j;                  // T%32==0 in harness; clamp for safety
            r = (r < T) ? r : (T - 1);
            g[j] = ((const float4*)(logits + ((size_t)r << 8)))[lane];
        }
        #pragma unroll
        for (int j = 0; j < 8; ++j)
            xw[(j << 6) | (lane ^ j)] = g[j];
        // wave-local: each wave reads only its own region; lgkmcnt (inserted by
        // the compiler for the aliasing ds ops) orders write -> read. No barrier.
    }

    const float* brw = bias + s * 32;

    float    v[8][4];
    unsigned pix[8];   // 4 expert indices per chunk, byte-packed (byte k = idx of v[c][k])

    // ---- fetch my 32 experts from LDS, exact sigmoid, add bias ----
    #pragma unroll
    for (int c = 0; c < 8; ++c) {
        // my chunk (s*8+c) of token tw sits at slot tw*64 + ((s*8+c) ^ tw)
        float4 l = xw[(tw << 6) | (s << 3) | (c ^ tw)];
        float4 b = ((const float4*)brw)[c];
        #pragma unroll
        for (int k = 0; k < 4; ++k) {
            float x = (&l.x)[k];
            v[c][k] = 1.0f / (1.0f + expf(-x)) + (&b.x)[k];
        }
        pix[c] = (unsigned)(s * 32 + c * 4) * 0x01010101u + 0x03020100u;
    }

    // ---- group score: sum of top-2 of my 32 biased values (med3 trick) ----
    float t1 = NEGINF, t2 = NEGINF;
    #pragma unroll
    for (int c = 0; c < 8; ++c) {
        #pragma unroll
        for (int k = 0; k < 4; ++k) {
            float val = v[c][k];
            t2 = __builtin_amdgcn_fmed3f(t1, t2, val);  // new 2nd-best (t1>=t2 invariant)
            t1 = fmaxf(t1, val);
        }
    }
    const float gs = t1 + t2;

    // ---- rank my group among the 8; keep top-4 ----
    // xor1/2/3 via DPP; xor4..7 = one swizzle + DPP on its result.
    int rank = 0;
    {
        float g1 = DPPF(gs, QP_X1);
        float g2 = DPPF(gs, QP_X2);
        float g3 = DPPF(gs, QP_X3);
        float g4 = SWZF(gs, 4);
        float g5 = DPPF(g4, QP_X1);
        float g6 = DPPF(g4, QP_X2);
        float g7 = DPPF(g4, QP_X3);
        // partner j = s^m; on tie lower group id wins: j<s iff s has high bit of m.
        rank += (g1 > gs || (g1 == gs && (s & 1))) ? 1 : 0;
        rank += (g2 > gs || (g2 == gs && (s & 2))) ? 1 : 0;
        rank += (g3 > gs || (g3 == gs && (s & 2))) ? 1 : 0;
        rank += (g4 > gs || (g4 == gs && (s & 4))) ? 1 : 0;
        rank += (g5 > gs || (g5 == gs && (s & 4))) ? 1 : 0;
        rank += (g6 > gs || (g6 == gs && (s & 4))) ? 1 : 0;
        rank += (g7 > gs || (g7 == gs && (s & 4))) ? 1 : 0;
    }
    const bool selected = rank < 4;
    // NOTE: no bulk NEGINF masking -- unselected lanes sort/tournament their
    // real values but are gated to NEGINF right before the cross-lane argmax.

    // ---- sort each chunk of 4 descending (ties -> lower idx first) ----
    #pragma unroll
    for (int c = 0; c < 8; ++c) {
        #define CE(A, B, KM) { \
            unsigned p  = pix[c]; \
            unsigned ia = (p >> (8*(A))) & 0xFFu; \
            unsigned ib = (p >> (8*(B))) & 0xFFu; \
            bool sw = (v[c][A] < v[c][B]) || (v[c][A] == v[c][B] && ia > ib); \
            float hv = sw ? v[c][B] : v[c][A]; \
            float lv = sw ? v[c][A] : v[c][B]; \
            v[c][A] = hv; v[c][B] = lv; \
            unsigned ps = (p & (KM)) | (ia << (8*(B))) | (ib << (8*(A))); \
            pix[c] = sw ? ps : p; \
        }
        CE(0,1,0xFFFF0000u) CE(2,3,0x0000FFFFu)
        CE(0,2,0xFF00FF00u) CE(1,3,0x00FF00FFu) CE(1,2,0xFF0000FFu)
        #undef CE
    }

    // ---- 8 rounds: global argmax over 64 stream heads, advance winner ----
    float keepV = 0.0f; int keepI = 0;
    const int sbase8 = s << 3;
    #pragma unroll
    for (int r = 0; r < 8; ++r) {
        // depth-3 tournament over 8 chunk heads; strict > keeps left (lower
        // chunk = lower index) on ties -> lowest-index-first.
        #define PICK(av, ai, bv_, bi_, rv, ri) { \
            bool t = ((bv_) > (av)); \
            rv = t ? (bv_) : (av); ri = t ? (bi_) : (ai); }
        float w0v, w1v, w2v, w3v, x0v, x1v, bv;
        int   w0i, w1i, w2i, w3i, x0i, x1i, bi;
        PICK(v[0][0], (int)(pix[0] & 0xFFu), v[1][0], (int)(pix[1] & 0xFFu), w0v, w0i)
        PICK(v[2][0], (int)(pix[2] & 0xFFu), v[3][0], (int)(pix[3] & 0xFFu), w1v, w1i)
        PICK(v[4][0], (int)(pix[4] & 0xFFu), v[5][0], (int)(pix[5] & 0xFFu), w2v, w2i)
        PICK(v[6][0], (int)(pix[6] & 0xFFu), v[7][0], (int)(pix[7] & 0xFFu), w3v, w3i)
        PICK(w0v, w0i, w1v, w1i, x0v, x0i)
        PICK(w2v, w2i, w3v, w3i, x1v, x1i)
        PICK(x0v, x0i, x1v, x1i, bv, bi)
        #undef PICK
        // gate unselected groups out of the global argmax (replaces 32-wide mask)
        bv = selected ? bv : NEGINF;
        // 8-lane butterfly argmax; index tie-break for cross-lane consistency.
        // xor1/xor2 on DPP (no LDS latency), xor4 on ds_swizzle.
        { float ov = DPPF(bv, QP_X1); int oi = DPPI(bi, QP_X1);
          bool t = (ov > bv) || (ov == bv && oi < bi); bv = t ? ov : bv; bi = t ? oi : bi; }
        { float ov = DPPF(bv, QP_X2); int oi = DPPI(bi, QP_X2);
          bool t = (ov > bv) || (ov == bv && oi < bi); bv = t ? ov : bv; bi = t ? oi : bi; }
        { float ov = SWZF(bv, 4);     int oi = SWZI(bi, 4);
          bool t = (ov > bv) || (ov == bv && oi < bi); bv = t ? ov : bv; bi = t ? oi : bi; }
        if (s == r) { keepV = bv; keepI = bi; }
        const int d = (bi >> 2) - sbase8;   // my chunk index if winner is mine
        #pragma unroll
        for (int c = 0; c < 8; ++c) {
            bool hit = (d == c);
            v[c][0] = hit ? v[c][1] : v[c][0];
            v[c][1] = hit ? v[c][2] : v[c][1];
            v[c][2] = hit ? v[c][3] : v[c][2];
            v[c][3] = hit ? NEGINF  : v[c][3];
            pix[c]  = hit ? (pix[c] >> 8) : pix[c];   // next head index slides to byte 0
        }
    }

    // ---- recover sigmoid score, renormalize, scale, store (coalesced) ----
    float w = keepV - bias[keepI];
    float sum = w;
    sum += DPPF(sum, QP_X1);   // same reduction tree as before: xor1, xor2, xor4
    sum += DPPF(sum, QP_X2);
    sum += SWZF(sum, 4);
    w = w / (sum + 1e-20f) * 2.5f;

    if (token < T) {
        const size_t o = (size_t)blockIdx.x * 256 + tid;  // == token*8 + s
        out_w[o]  = w;
        out_id[o] = (float)keepI;
    }
}

extern "C" void kernel_launch(void* const* d_in, const int* in_sizes, int n_in,
                              void* d_out, int out_size, void* d_ws, size_t ws_size,
                              hipStream_t stream) {
    const float* logits = (const float*)d_in[0];
    const float* bias   = (const float*)d_in[1];
    const int E = in_sizes[1];          // 256
    const int T = in_sizes[0] / E;      // 131072
    float* out_w  = (float*)d_out;
    float* out_id = out_w + (size_t)T * 8;
    const int blocks = (T + 31) / 32;
    router_topk_kernel<<<blocks, 256, 0, stream>>>(logits, bias, out_w, out_id, T);
}

// Round 4
// 202.003 us; speedup vs baseline: 1.0339x; 1.0339x over previous
//
#include <hip/hip_runtime.h>
#include <math.h>

// Group-limited MoE router, T=131072 tokens x E=256 experts.
// 8 lanes per token. Round 7: post-selection COMPACTION. After the 4 winning
// groups are known, their 128 biased values are redistributed over all 8
// lanes (4 chunks of 4 each) through the existing LDS buffer. Chunk sorts
// halve (40->20 CE) and each extraction round shrinks (7->3 PICKs, 8->4
// chunk advance, no NEGINF gate) -- ~30% fewer VALU ops, which is the
// measured invariant (~55us of VALU issue) pinning the benched kernel.
// Sigmoid + every compare/tie rule bit-identical to the passing Round-6.

#define SWZF(x, mask) __int_as_float(__builtin_amdgcn_ds_swizzle(__float_as_int(x), (((mask) << 10) | 0x1F)))
#define SWZI(x, mask) __builtin_amdgcn_ds_swizzle((x), (((mask) << 10) | 0x1F))
// DPP quad_perm: xor1=[1,0,3,2]=0xB1, xor2=[2,3,0,1]=0x4E, xor3=[3,2,1,0]=0x1B.
// Tokens own 8 aligned lanes -> quads never cross tokens.
#define DPPF(x, ctrl) __int_as_float(__builtin_amdgcn_update_dpp(__float_as_int(x), __float_as_int(x), (ctrl), 0xF, 0xF, true))
#define DPPI(x, ctrl) __builtin_amdgcn_update_dpp((x), (x), (ctrl), 0xF, 0xF, true)
#define QP_X1 0xB1
#define QP_X2 0x4E
#define QP_X3 0x1B

__global__ __launch_bounds__(256) void router_topk_kernel(
    const float* __restrict__ logits,
    const float* __restrict__ bias,
    float* __restrict__ out_w,
    float* __restrict__ out_id,
    int T)
{
    const float NEGINF = -__builtin_inff();
    const int tid  = threadIdx.x;
    const int lane = tid & 63;
    const int wid  = tid >> 6;                  // wave id within block (0..3)
    const int s    = tid & 7;                   // expert-group owned by this lane
    const int tw   = (tid >> 3) & 7;            // token-in-wave (0..7)
    const int token = blockIdx.x * 32 + (tid >> 3);
    const int wtok0 = blockIdx.x * 32 + (wid << 3);

    // 4 waves x 512 float4 slots (8KB/wave) = 32KB; reused twice:
    // phase 1: raw logits staging (coalesced load + xor transpose)
    // phase 2: biased values in [tw][chunk][s^tw] layout for compaction
    __shared__ float4 xp[2048];
    float4* xw = xp + (wid << 9);

    // ---- coalesced load: instruction j covers token (wtok0+j)'s full 1KB row
    {
        float4 gbuf[8];
        #pragma unroll
        for (int j = 0; j < 8; ++j) {
            int r = wtok0 + j;
            r = (r < T) ? r : (T - 1);
            gbuf[j] = ((const float4*)(logits + ((size_t)r << 8)))[lane];
        }
        #pragma unroll
        for (int j = 0; j < 8; ++j)
            xw[(j << 6) | (lane ^ j)] = gbuf[j];
        // wave-local buffer; lockstep + compiler lgkmcnt orders write->read.
    }

    const float* brw = bias + s * 32;
    float v[8][4];

    // ---- fetch my 32 experts, exact sigmoid, add bias ----
    #pragma unroll
    for (int c = 0; c < 8; ++c) {
        float4 l = xw[(tw << 6) | (s << 3) | (c ^ tw)];
        float4 b = ((const float4*)brw)[c];
        #pragma unroll
        for (int k = 0; k < 4; ++k) {
            float x = (&l.x)[k];
            v[c][k] = 1.0f / (1.0f + expf(-x)) + (&b.x)[k];
        }
    }

    // ---- group score: sum of top-2 of my 32 biased values (med3 trick) ----
    float t1 = NEGINF, t2 = NEGINF;
    #pragma unroll
    for (int c = 0; c < 8; ++c) {
        #pragma unroll
        for (int k = 0; k < 4; ++k) {
            float val = v[c][k];
            t2 = __builtin_amdgcn_fmed3f(t1, t2, val);
            t1 = fmaxf(t1, val);
        }
    }
    const float gs = t1 + t2;

    // ---- write biased values back: slot = [tw][c][s^tw].
    // Per write instr (c fixed) lanes s=0..7 hit 8 consecutive float4 -> no
    // bank conflict; ^tw spreads the later gather across bank groups.
    #pragma unroll
    for (int c = 0; c < 8; ++c)
        xw[(tw << 6) | (c << 3) | (s ^ tw)] = make_float4(v[c][0], v[c][1], v[c][2], v[c][3]);

    // ---- rank my group among the 8; keep top-4 ----
    int rank = 0;
    {
        float g1 = DPPF(gs, QP_X1);
        float g2 = DPPF(gs, QP_X2);
        float g3 = DPPF(gs, QP_X3);
        float g4 = SWZF(gs, 4);
        float g5 = DPPF(g4, QP_X1);
        float g6 = DPPF(g4, QP_X2);
        float g7 = DPPF(g4, QP_X3);
        rank += (g1 > gs || (g1 == gs && (s & 1))) ? 1 : 0;
        rank += (g2 > gs || (g2 == gs && (s & 2))) ? 1 : 0;
        rank += (g3 > gs || (g3 == gs && (s & 2))) ? 1 : 0;
        rank += (g4 > gs || (g4 == gs && (s & 4))) ? 1 : 0;
        rank += (g5 > gs || (g5 == gs && (s & 4))) ? 1 : 0;
        rank += (g6 > gs || (g6 == gs && (s & 4))) ? 1 : 0;
        rank += (g7 > gs || (g7 == gs && (s & 4))) ? 1 : 0;
    }
    const bool selected = rank < 4;   // ranks are a permutation -> exactly 4

    // ---- 8-bit selected-group mask, shared by all 8 lanes of the token ----
    int msk = selected ? (1 << s) : 0;
    msk |= DPPI(msk, QP_X1);
    msk |= DPPI(msk, QP_X2);
    msk |= SWZI(msk, 4);

    // ---- my source group = (s>>1)-th set bit of msk (ascending group id) ----
    unsigned m0 = (unsigned)msk;
    int g0 = __builtin_ctz(m0);
    unsigned m1 = m0 & (m0 - 1);
    int g1 = __builtin_ctz(m1);
    unsigned m2 = m1 & (m1 - 1);
    int g2 = __builtin_ctz(m2);
    unsigned m3 = m2 & (m2 - 1);
    int g3 = __builtin_ctz(m3);
    int ga = (s & 2) ? g1 : g0;
    int gb = (s & 2) ? g3 : g2;
    const int grp = (s & 4) ? gb : ga;
    const int h4  = (s & 1) << 2;               // half*4 (chunk offset)

    // ---- gather my 4 redistributed chunks (16 values of group grp) ----
    float    f[4][4];
    unsigned pix[4];   // byte k of pix[j] = expert idx of f[j][k]
    {
        const int rb = (tw << 6) | (grp ^ tw);
        #pragma unroll
        for (int j = 0; j < 4; ++j) {
            float4 nb = xw[rb | ((h4 + j) << 3)];
            f[j][0] = nb.x; f[j][1] = nb.y; f[j][2] = nb.z; f[j][3] = nb.w;
        }
        const unsigned ebase = (unsigned)(grp * 32 + (h4 << 2)); // grp*32 + h*16
        const unsigned pbase = ebase * 0x01010101u;
        pix[0] = pbase + 0x03020100u;
        pix[1] = pbase + 0x07060504u;
        pix[2] = pbase + 0x0B0A0908u;
        pix[3] = pbase + 0x0F0E0D0Cu;
    }

    // ---- sort each chunk of 4 descending (ties -> lower idx first) ----
    #pragma unroll
    for (int c = 0; c < 4; ++c) {
        #define CE(A, B, KM) { \
            unsigned p  = pix[c]; \
            unsigned ia = (p >> (8*(A))) & 0xFFu; \
            unsigned ib = (p >> (8*(B))) & 0xFFu; \
            bool sw = (f[c][A] < f[c][B]) || (f[c][A] == f[c][B] && ia > ib); \
            float hv = sw ? f[c][B] : f[c][A]; \
            float lv = sw ? f[c][A] : f[c][B]; \
            f[c][A] = hv; f[c][B] = lv; \
            unsigned ps = (p & (KM)) | (ia << (8*(B))) | (ib << (8*(A))); \
            pix[c] = sw ? ps : p; \
        }
        CE(0,1,0xFFFF0000u) CE(2,3,0x0000FFFFu)
        CE(0,2,0xFF00FF00u) CE(1,3,0x00FF00FFu) CE(1,2,0xFF0000FFu)
        #undef CE
    }

    // ---- 8 rounds: global argmax over 32 stream heads, advance winner ----
    // All lanes hold live selected data -> no gating. Strict > keeps left
    // (lower chunk = lower expert idx) on ties; idx ascends across lanes.
    float keepV = 0.0f; int keepI = 0;
    #pragma unroll
    for (int r = 0; r < 8; ++r) {
        const int h0 = (int)(pix[0] & 0xFFu);
        const int h1 = (int)(pix[1] & 0xFFu);
        const int h2 = (int)(pix[2] & 0xFFu);
        const int h3 = (int)(pix[3] & 0xFFu);
        float w0v, w1v, bv; int w0i, w1i, bi;
        { bool t = (f[1][0] > f[0][0]); w0v = t ? f[1][0] : f[0][0]; w0i = t ? h1 : h0; }
        { bool t = (f[3][0] > f[2][0]); w1v = t ? f[3][0] : f[2][0]; w1i = t ? h3 : h2; }
        { bool t = (w1v > w0v);         bv  = t ? w1v : w0v;         bi  = t ? w1i : w0i; }
        // 8-lane butterfly argmax; idx tie-break for cross-lane consistency
        { float ov = DPPF(bv, QP_X1); int oi = DPPI(bi, QP_X1);
          bool t = (ov > bv) || (ov == bv && oi < bi); bv = t ? ov : bv; bi = t ? oi : bi; }
        { float ov = DPPF(bv, QP_X2); int oi = DPPI(bi, QP_X2);
          bool t = (ov > bv) || (ov == bv && oi < bi); bv = t ? ov : bv; bi = t ? oi : bi; }
        { float ov = SWZF(bv, 4);     int oi = SWZI(bi, 4);
          bool t = (ov > bv) || (ov == bv && oi < bi); bv = t ? ov : bv; bi = t ? oi : bi; }
        if (s == r) { keepV = bv; keepI = bi; }
        // advance: the unique live chunk whose head idx == bi pops one.
        // (Exhausted chunks have head byte 0; a false hit only shifts NEGINFs.)
        {
            bool hit = (h0 == bi);
            f[0][0] = hit ? f[0][1] : f[0][0];
            f[0][1] = hit ? f[0][2] : f[0][1];
            f[0][2] = hit ? f[0][3] : f[0][2];
            f[0][3] = hit ? NEGINF  : f[0][3];
            pix[0]  = hit ? (pix[0] >> 8) : pix[0];
        }
        {
            bool hit = (h1 == bi);
            f[1][0] = hit ? f[1][1] : f[1][0];
            f[1][1] = hit ? f[1][2] : f[1][1];
            f[1][2] = hit ? f[1][3] : f[1][2];
            f[1][3] = hit ? NEGINF  : f[1][3];
            pix[1]  = hit ? (pix[1] >> 8) : pix[1];
        }
        {
            bool hit = (h2 == bi);
            f[2][0] = hit ? f[2][1] : f[2][0];
            f[2][1] = hit ? f[2][2] : f[2][1];
            f[2][2] = hit ? f[2][3] : f[2][2];
            f[2][3] = hit ? NEGINF  : f[2][3];
            pix[2]  = hit ? (pix[2] >> 8) : pix[2];
        }
        {
            bool hit = (h3 == bi);
            f[3][0] = hit ? f[3][1] : f[3][0];
            f[3][1] = hit ? f[3][2] : f[3][1];
            f[3][2] = hit ? f[3][3] : f[3][2];
            f[3][3] = hit ? NEGINF  : f[3][3];
            pix[3]  = hit ? (pix[3] >> 8) : pix[3];
        }
    }

    // ---- recover sigmoid score, renormalize, scale, store (coalesced) ----
    float w = keepV - bias[keepI];
    float sum = w;
    sum += DPPF(sum, QP_X1);
    sum += DPPF(sum, QP_X2);
    sum += SWZF(sum, 4);
    w = w / (sum + 1e-20f) * 2.5f;

    if (token < T) {
        const size_t o = (size_t)blockIdx.x * 256 + tid;  // == token*8 + s
        out_w[o]  = w;
        out_id[o] = (float)keepI;
    }
}

extern "C" void kernel_launch(void* const* d_in, const int* in_sizes, int n_in,
                              void* d_out, int out_size, void* d_ws, size_t ws_size,
                              hipStream_t stream) {
    const float* logits = (const float*)d_in[0];
    const float* bias   = (const float*)d_in[1];
    const int E = in_sizes[1];          // 256
    const int T = in_sizes[0] / E;      // 131072
    float* out_w  = (float*)d_out;
    float* out_id = out_w + (size_t)T * 8;
    const int blocks = (T + 31) / 32;
    router_topk_kernel<<<blocks, 256, 0, stream>>>(logits, bias, out_w, out_id, T);
}